// Round 7
// baseline (569.195 us; speedup 1.0000x reference)
//
#include <hip/hip_runtime.h>
#include <hip/hip_bf16.h>

typedef __attribute__((ext_vector_type(4))) float f32x4;
typedef __attribute__((ext_vector_type(2))) unsigned int u32x2;
typedef __attribute__((ext_vector_type(8))) short s16x8;
typedef __attribute__((ext_vector_type(4))) short s16x4;
typedef __attribute__((ext_vector_type(8))) __bf16 bf16v8;

// LDS layout (bytes)
#define LDS_XS 0        // 32768: x window bf16 [64][256] swz512; phase2+: attn_lo
#define LDS_QS 32768    // 32768: Q bf16 [64][256] (pre-scaled) swz512; phase2+: attn_hi
#define LDS_KS 65536    // 32768: K bf16 [64][256], swz512
#define LDS_VT 98304    // 40960: V^T bf16 [256 d][64 tok], stride 160 (no xor)
#define LDS_PR 139264   // 20480: P' bf16 [2 hsel][64 p][64 q], stride 160 (no xor)
#define LDS_TOT 159744
#define VT_STR 160
#define PR_STR 160

__device__ __forceinline__ f32x4 mfma16(s16x8 a, s16x8 b, f32x4 c) {
  return __builtin_amdgcn_mfma_f32_16x16x32_bf16(
      __builtin_bit_cast(bf16v8, a), __builtin_bit_cast(bf16v8, b), c, 0, 0, 0);
}

// HW pair convert: low16 = bf16(a), high16 = bf16(b), RNE
__device__ __forceinline__ unsigned int cvt2(float a, float b) {
  __hip_bfloat162 r = __float22bfloat162_rn(make_float2(a, b));
  unsigned int u;
  __builtin_memcpy(&u, &r, 4);
  return u;
}

__device__ __forceinline__ short f2bf(float f) {
  unsigned u = __float_as_uint(f);
  u += 0x7fffu + ((u >> 16) & 1u);
  return (short)(u >> 16);
}
__device__ __forceinline__ float bf2f(short h) {
  return __uint_as_float(((unsigned)(unsigned short)h) << 16);
}

__device__ __forceinline__ int swz512(int row, int colByte) {
  return row * 512 + (colByte ^ ((row & 7) << 4));
}

// Prep: WqkvT[n][k] bf16 (768x256); WoutT hi/lo [n][k] bf16 (256x256);
// RELT[var][h][qt][strip][lane][r] f32 = masked rel_pos in simT C-frag order.
__global__ void prep_w(const float* __restrict__ Wqkv, const float* __restrict__ Wout,
                       const float* __restrict__ relp,
                       short* __restrict__ wqkvT, short* __restrict__ woutTh,
                       short* __restrict__ woutTl, float* __restrict__ relt) {
  int t = blockIdx.x * 256 + threadIdx.x;
  if (t < 768 * 256) {
    int n = t >> 8, k = t & 255;
    wqkvT[t] = f2bf(Wqkv[k * 768 + n]);
  } else if (t < 768 * 256 + 256 * 256) {
    int t2 = t - 768 * 256;
    int n = t2 >> 8, k = t2 & 255;
    float wv = Wout[k * 256 + n];
    short hi = f2bf(wv);
    woutTh[t2] = hi;
    woutTl[t2] = f2bf(wv - bf2f(hi));
  } else {
    int u = t - 768 * 256 - 256 * 256;   // 0 .. 131071
    int r = u & 3, l = (u >> 2) & 63, strip = (u >> 8) & 3;
    int qt = (u >> 10) & 3, h = (u >> 12) & 7, var = (u >> 15) & 3;
    int p = strip * 16 + (l & 15);
    int q = qt * 16 + ((l >> 4) << 2) + r;
    int pi = p >> 3, pj = p & 7, qi = q >> 3, qj = q & 7;
    bool mrow = (var >> 1) & 1, mcol = var & 1;
    bool mk = (mrow && ((pi < 4) != (qi < 4))) || (mcol && ((pj < 4) != (qj < 4)));
    relt[u] = mk ? -1e30f : relp[h * 225 + (pi - qi + 7) * 15 + (pj - qj + 7)];
  }
}

// One block per (batch, window). 512 threads = 8 waves.
__global__ __launch_bounds__(512, 2) void swin_mfma(
    const float* __restrict__ x, const float* __restrict__ bqkv,
    const float* __restrict__ bout,
    const short* __restrict__ wqkvT, const short* __restrict__ woutTh,
    const short* __restrict__ woutTl, const float* __restrict__ relt,
    float* __restrict__ out)
{
  __shared__ __align__(16) char lds[LDS_TOT];

  const int tx = threadIdx.x;
  const int w  = tx >> 6;         // wave 0..7
  const int l  = tx & 63;         // lane
  const int g  = l >> 4;          // k-group 0..3
  const int li = l & 15;          // row/col within fragment

  const int b   = blockIdx.x >> 10;
  const int wdw = blockIdx.x & 1023;
  const int wh  = wdw >> 5, wwi = wdw & 31;

  // ---- Phase 0: stage x window (rolled -4) as bf16 into LDS ----
  for (int i = 0; i < 8; ++i) {
    int idx = tx + i * 512;       // 0..4095
    int p = idx >> 6, c4 = idx & 63;
    int pi = p >> 3, pj = p & 7;
    int sr = (wh * 8 + pi + 4) & 255;
    int sc = (wwi * 8 + pj + 4) & 255;
    f32x4 v = *(const f32x4*)(x + ((((size_t)b * 256 + sr) * 256 + sc) * 256 + c4 * 4));
    u32x2 uu;
    uu.x = cvt2(v[0], v[1]);
    uu.y = cvt2(v[2], v[3]);
    *(u32x2*)(lds + LDS_XS + swz512(p, c4 * 8)) = uu;
  }
  __syncthreads();

  // ---- Phase 1: QKV GEMM. Wave w: Q/K col-blocks w*4..w*4+3 (swapped operands,
  //      C = [outcol][token]); V col-blocks w*2, w*2+1 (normal, C = [token][vcol]). ----
  {
    f32x4 acc[6][4];
    #pragma unroll
    for (int j = 0; j < 6; ++j)
      #pragma unroll
      for (int rb = 0; rb < 4; ++rb)
        acc[j][rb] = (f32x4){0.f, 0.f, 0.f, 0.f};

    int ocol[6];
    #pragma unroll
    for (int j = 0; j < 4; ++j) ocol[j] = (w * 4 + j) * 16 + li;
    #pragma unroll
    for (int j = 4; j < 6; ++j) ocol[j] = 512 + (w * 2 + (j - 4)) * 16 + li;

    s16x8 bcur[6], bnext[6];
    #pragma unroll
    for (int j = 0; j < 6; ++j)
      bcur[j] = *(const s16x8*)(wqkvT + (size_t)ocol[j] * 256 + g * 8);

    #pragma unroll
    for (int kk = 0; kk < 8; ++kk) {
      s16x8 a[4];
      #pragma unroll
      for (int rb = 0; rb < 4; ++rb)
        a[rb] = *(const s16x8*)(lds + LDS_XS + swz512(rb * 16 + li, kk * 64 + g * 16));
      if (kk < 7) {
        #pragma unroll
        for (int j = 0; j < 6; ++j)
          bnext[j] = *(const s16x8*)(wqkvT + (size_t)ocol[j] * 256 + (kk + 1) * 32 + g * 8);
      }
      #pragma unroll
      for (int j = 0; j < 4; ++j)          // Q,K: swapped -> C[outcol][token]
        #pragma unroll
        for (int rb = 0; rb < 4; ++rb)
          acc[j][rb] = mfma16(bcur[j], a[rb], acc[j][rb]);
      #pragma unroll
      for (int j = 4; j < 6; ++j)          // V: normal -> C[token][vcol]
        #pragma unroll
        for (int rb = 0; rb < 4; ++rb)
          acc[j][rb] = mfma16(a[rb], bcur[j], acc[j][rb]);
      if (kk < 7) {
        #pragma unroll
        for (int j = 0; j < 6; ++j) bcur[j] = bnext[j];
      }
    }

    // Packed b64 stores.
    #pragma unroll
    for (int j = 0; j < 4; ++j) {          // Q or K: row=token(rb*16+li), 4 consec cols
      const int cb = w * 4 + j;
      if (cb < 16) {                       // Q (pre-scaled)
        f32x4 bq = *(const f32x4*)(bqkv + cb * 16 + g * 4);
        #pragma unroll
        for (int rb = 0; rb < 4; ++rb) {
          const float SC = 0.17677669529663687f;
          u32x2 uu;
          uu.x = cvt2((acc[j][rb][0] + bq[0]) * SC, (acc[j][rb][1] + bq[1]) * SC);
          uu.y = cvt2((acc[j][rb][2] + bq[2]) * SC, (acc[j][rb][3] + bq[3]) * SC);
          *(u32x2*)(lds + LDS_QS + swz512(rb * 16 + li, cb * 32 + g * 8)) = uu;
        }
      } else {                             // K
        f32x4 bk = *(const f32x4*)(bqkv + 256 + (cb - 16) * 16 + g * 4);
        #pragma unroll
        for (int rb = 0; rb < 4; ++rb) {
          u32x2 uu;
          uu.x = cvt2(acc[j][rb][0] + bk[0], acc[j][rb][1] + bk[1]);
          uu.y = cvt2(acc[j][rb][2] + bk[2], acc[j][rb][3] + bk[3]);
          *(u32x2*)(lds + LDS_KS + swz512(rb * 16 + li, (cb - 16) * 32 + g * 8)) = uu;
        }
      }
    }
    #pragma unroll
    for (int j = 4; j < 6; ++j) {          // V -> VT[d][token], padded stride
      const int d = (w * 2 + (j - 4)) * 16 + li;
      const float bv = bqkv[512 + d];
      #pragma unroll
      for (int rb = 0; rb < 4; ++rb) {
        u32x2 uu;
        uu.x = cvt2(acc[j][rb][0] + bv, acc[j][rb][1] + bv);
        uu.y = cvt2(acc[j][rb][2] + bv, acc[j][rb][3] + bv);
        *(u32x2*)(lds + LDS_VT + d * VT_STR + rb * 32 + g * 8) = uu;
      }
    }
  }
  __syncthreads();

  // ---- Phase 2: attention. Wave w: heads hp*2+(w>>2), rows (w&3)*16..+15. ----
  {
    const int rvar = ((wh == 31) ? 2 : 0) | ((wwi == 31) ? 1 : 0);
    const int hsel = w >> 2, strip = w & 3, p0 = strip * 16;
    const short ONE = (short)0x3F80;
    const s16x8 ones = {ONE, ONE, ONE, ONE, ONE, ONE, ONE, ONE};
    char* prbase = lds + LDS_PR + hsel * (64 * PR_STR);

    f32x4 rcn[4];
    #pragma unroll
    for (int qt = 0; qt < 4; ++qt)
      rcn[qt] = *(const f32x4*)(relt + ((((rvar * 8 + hsel) * 4 + qt) * 4 + strip) * 64 + l) * 4);

    #pragma unroll
    for (int hp = 0; hp < 4; ++hp) {
      const int h = hp * 2 + hsel;
      f32x4 rc[4];
      #pragma unroll
      for (int qt = 0; qt < 4; ++qt) rc[qt] = rcn[qt];

      // issue all LDS reads for this head up front
      s16x8 qf = *(const s16x8*)(lds + LDS_QS + swz512(p0 + li, h * 64 + g * 16));
      s16x8 kf[4];
      #pragma unroll
      for (int qt = 0; qt < 4; ++qt)
        kf[qt] = *(const s16x8*)(lds + LDS_KS + swz512(qt * 16 + li, h * 64 + g * 16));
      s16x8 vf[2][2];
      #pragma unroll
      for (int ks = 0; ks < 2; ++ks)
        #pragma unroll
        for (int dt = 0; dt < 2; ++dt)
          vf[ks][dt] = *(const s16x8*)(lds + LDS_VT + (h * 32 + dt * 16 + li) * VT_STR
                                       + ks * 64 + g * 16);
      // prefetch next head's rel_pos C-init (hides L2 latency)
      if (hp < 3) {
        #pragma unroll
        for (int qt = 0; qt < 4; ++qt)
          rcn[qt] = *(const f32x4*)(relt
              + ((((rvar * 8 + (h + 2)) * 4 + qt) * 4 + strip) * 64 + l) * 4);
      }

      f32x4 simT[4];
      #pragma unroll
      for (int qt = 0; qt < 4; ++qt) simT[qt] = mfma16(kf[qt], qf, rc[qt]);

      // P' = exp(simT) (no-max softmax; masked = exp(-1e30) = 0), packed b64 store
      #pragma unroll
      for (int qt = 0; qt < 4; ++qt) {
        u32x2 uu;
        uu.x = cvt2(__expf(simT[qt][0]), __expf(simT[qt][1]));
        uu.y = cvt2(__expf(simT[qt][2]), __expf(simT[qt][3]));
        *(u32x2*)(prbase + (p0 + li) * PR_STR + qt * 32 + g * 8) = uu;
      }

      s16x8 pf[2];
      #pragma unroll
      for (int ks = 0; ks < 2; ++ks)
        pf[ks] = *(const s16x8*)(prbase + (p0 + li) * PR_STR + ks * 64 + g * 16);

      __builtin_amdgcn_s_setprio(1);
      f32x4 s = (f32x4){0.f, 0.f, 0.f, 0.f};
      f32x4 at0 = (f32x4){0.f, 0.f, 0.f, 0.f};
      f32x4 at1 = (f32x4){0.f, 0.f, 0.f, 0.f};
      #pragma unroll
      for (int ks = 0; ks < 2; ++ks) {
        s   = mfma16(ones, pf[ks], s);
        at0 = mfma16(vf[ks][0], pf[ks], at0);
        at1 = mfma16(vf[ks][1], pf[ks], at1);
      }
      __builtin_amdgcn_s_setprio(0);
      const float rinv = 1.0f / s[0];

      // attn hi/lo packed stores: row = p (p0+li), 4 consecutive channels
      #pragma unroll
      for (int dt = 0; dt < 2; ++dt) {
        const f32x4 at = dt ? at1 : at0;
        float v0 = at[0] * rinv, v1 = at[1] * rinv;
        float v2 = at[2] * rinv, v3 = at[3] * rinv;
        unsigned int uh0 = cvt2(v0, v1), uh1 = cvt2(v2, v3);
        float l0 = v0 - __uint_as_float(uh0 << 16);
        float l1 = v1 - __uint_as_float(uh0 & 0xffff0000u);
        float l2 = v2 - __uint_as_float(uh1 << 16);
        float l3 = v3 - __uint_as_float(uh1 & 0xffff0000u);
        u32x2 hh, ll;
        hh.x = uh0; hh.y = uh1;
        ll.x = cvt2(l0, l1); ll.y = cvt2(l2, l3);
        const int cByte = h * 64 + dt * 32 + g * 8;
        *(u32x2*)(lds + LDS_QS + swz512(p0 + li, cByte)) = hh;
        *(u32x2*)(lds + LDS_XS + swz512(p0 + li, cByte)) = ll;
      }
    }
  }
  __syncthreads();

  // ---- Phase 3: out-proj, 3-term split-bf16; wave = (row-half rr, col-quarter cc) ----
  {
    const int rr = w >> 2;      // 0..1
    const int cc = w & 3;       // 0..3
    f32x4 acc2[4][2];
    #pragma unroll
    for (int c = 0; c < 4; ++c)
      #pragma unroll
      for (int rb2 = 0; rb2 < 2; ++rb2)
        acc2[c][rb2] = (f32x4){0.f, 0.f, 0.f, 0.f};

    s16x8 bhc[4], blc[4], bhn[4], bln[4];
    #pragma unroll
    for (int c = 0; c < 4; ++c) {
      const size_t base = (size_t)((cc * 4 + c) * 16 + li) * 256 + g * 8;
      bhc[c] = *(const s16x8*)(woutTh + base);
      blc[c] = *(const s16x8*)(woutTl + base);
    }

    #pragma unroll
    for (int kk = 0; kk < 8; ++kk) {
      s16x8 ah[2], al[2];
      #pragma unroll
      for (int rb2 = 0; rb2 < 2; ++rb2) {
        const int off = swz512((rr * 2 + rb2) * 16 + li, kk * 64 + g * 16);
        ah[rb2] = *(const s16x8*)(lds + LDS_QS + off);
        al[rb2] = *(const s16x8*)(lds + LDS_XS + off);
      }
      if (kk < 7) {
        #pragma unroll
        for (int c = 0; c < 4; ++c) {
          const size_t base = (size_t)((cc * 4 + c) * 16 + li) * 256 + (kk + 1) * 32 + g * 8;
          bhn[c] = *(const s16x8*)(woutTh + base);
          bln[c] = *(const s16x8*)(woutTl + base);
        }
      }
      #pragma unroll
      for (int c = 0; c < 4; ++c)
        #pragma unroll
        for (int rb2 = 0; rb2 < 2; ++rb2) {
          acc2[c][rb2] = mfma16(ah[rb2], bhc[c], acc2[c][rb2]);
          acc2[c][rb2] = mfma16(al[rb2], bhc[c], acc2[c][rb2]);
          acc2[c][rb2] = mfma16(ah[rb2], blc[c], acc2[c][rb2]);
        }
      if (kk < 7) {
        #pragma unroll
        for (int c = 0; c < 4; ++c) { bhc[c] = bhn[c]; blc[c] = bln[c]; }
      }
    }

    #pragma unroll
    for (int c = 0; c < 4; ++c) {
      const int n = (cc * 4 + c) * 16 + li;
      const float bo = bout[n];
      #pragma unroll
      for (int rb2 = 0; rb2 < 2; ++rb2)
        #pragma unroll
        for (int r = 0; r < 4; ++r) {
          int m = (rr * 2 + rb2) * 16 + g * 4 + r;
          int pi = m >> 3, pj = m & 7;
          int dr = (wh * 8 + pi + 4) & 255;
          int dc = (wwi * 8 + pj + 4) & 255;
          out[(((size_t)b * 256 + dr) * 256 + dc) * 256 + n] = acc2[c][rb2][r] + bo;
        }
    }
  }
}

extern "C" void kernel_launch(void* const* d_in, const int* in_sizes, int n_in,
                              void* d_out, int out_size, void* d_ws, size_t ws_size,
                              hipStream_t stream) {
  (void)in_sizes; (void)n_in; (void)out_size; (void)ws_size;
  const float* x    = (const float*)d_in[0];
  const float* Wqkv = (const float*)d_in[1];
  const float* bqkv = (const float*)d_in[2];
  const float* relp = (const float*)d_in[3];
  const float* Wout = (const float*)d_in[4];
  const float* bout = (const float*)d_in[5];
  float* out = (float*)d_out;

  short* wqkvT  = (short*)d_ws;                 // 768*256 bf16
  short* woutTh = wqkvT + 768 * 256;            // 256*256 bf16
  short* woutTl = woutTh + 256 * 256;           // 256*256 bf16
  float* relt   = (float*)(woutTl + 256 * 256); // 4*8*4*4*256 f32 = 512KB

  hipLaunchKernelGGL(prep_w, dim3(1536), dim3(256), 0, stream,
                     Wqkv, Wout, relp, wqkvT, woutTh, woutTl, relt);
  hipLaunchKernelGGL(swin_mfma, dim3(4096), dim3(512), 0, stream,
                     x, bqkv, bout, wqkvT, woutTh, woutTl, relt, out);
}

// Round 8
// 408.577 us; speedup vs baseline: 1.3931x; 1.3931x over previous
//
#include <hip/hip_runtime.h>
#include <hip/hip_bf16.h>

typedef __attribute__((ext_vector_type(4))) float f32x4;
typedef __attribute__((ext_vector_type(2))) unsigned int u32x2;
typedef __attribute__((ext_vector_type(8))) short s16x8;
typedef __attribute__((ext_vector_type(8))) __bf16 bf16v8;
typedef __attribute__((ext_vector_type(8))) _Float16 f16v8;

// LDS layout (bytes)
#define LDS_XS 0        // 32768: x window bf16 [64][256] swz512; phase2+: attn fp16
#define LDS_QS 32768    // 32768: Q bf16 [64][256] (pre-scaled) swz512
#define LDS_KS 65536    // 32768: K bf16 [64][256], swz512
#define LDS_VT 98304    // 32768: V^T bf16 [256][64], swz128
#define LDS_PR 131072   // 16384: P' bf16 [2 hsel][64 p][64 q], swz128
#define LDS_TOT 147456

__device__ __forceinline__ f32x4 mfma16(s16x8 a, s16x8 b, f32x4 c) {
  return __builtin_amdgcn_mfma_f32_16x16x32_bf16(
      __builtin_bit_cast(bf16v8, a), __builtin_bit_cast(bf16v8, b), c, 0, 0, 0);
}
__device__ __forceinline__ f32x4 mfma16h(s16x8 a, s16x8 b, f32x4 c) {
  return __builtin_amdgcn_mfma_f32_16x16x32_f16(
      __builtin_bit_cast(f16v8, a), __builtin_bit_cast(f16v8, b), c, 0, 0, 0);
}

// HW pair converts
__device__ __forceinline__ unsigned int cvt2(float a, float b) {   // 2x bf16, RNE
  __hip_bfloat162 r = __float22bfloat162_rn(make_float2(a, b));
  unsigned int u;
  __builtin_memcpy(&u, &r, 4);
  return u;
}
__device__ __forceinline__ unsigned int cvt2h(float a, float b) {  // 2x fp16, RTZ
  auto r = __builtin_amdgcn_cvt_pkrtz(a, b);
  unsigned int u;
  __builtin_memcpy(&u, &r, 4);
  return u;
}

__device__ __forceinline__ short f2bf(float f) {
  unsigned u = __float_as_uint(f);
  u += 0x7fffu + ((u >> 16) & 1u);
  return (short)(u >> 16);
}

__device__ __forceinline__ int swz512(int row, int colByte) {
  return row * 512 + (colByte ^ ((row & 7) << 4));
}
__device__ __forceinline__ int swz128(int row, int colByte) {
  return row * 128 + (colByte ^ ((row & 7) << 4));
}

// Prep: WqkvT[n][k] bf16 (768x256); WoutT[n][k] fp16 (256x256);
// RELT[var][h][qt][strip][lane][r] f32 = masked rel_pos in simT C-frag order.
__global__ void prep_w(const float* __restrict__ Wqkv, const float* __restrict__ Wout,
                       const float* __restrict__ relp,
                       short* __restrict__ wqkvT, short* __restrict__ wH,
                       float* __restrict__ relt) {
  int t = blockIdx.x * 256 + threadIdx.x;
  if (t < 768 * 256) {
    int n = t >> 8, k = t & 255;
    wqkvT[t] = f2bf(Wqkv[k * 768 + n]);
  } else if (t < 768 * 256 + 256 * 256) {
    int t2 = t - 768 * 256;
    int n = t2 >> 8, k = t2 & 255;
    _Float16 h = (_Float16)Wout[k * 256 + n];
    unsigned short us;
    __builtin_memcpy(&us, &h, 2);
    wH[t2] = (short)us;
  } else {
    int u = t - 768 * 256 - 256 * 256;   // 0 .. 131071
    int r = u & 3, l = (u >> 2) & 63, strip = (u >> 8) & 3;
    int qt = (u >> 10) & 3, h = (u >> 12) & 7, var = (u >> 15) & 3;
    int p = strip * 16 + (l & 15);
    int q = qt * 16 + ((l >> 4) << 2) + r;
    int pi = p >> 3, pj = p & 7, qi = q >> 3, qj = q & 7;
    bool mrow = (var >> 1) & 1, mcol = var & 1;
    bool mk = (mrow && ((pi < 4) != (qi < 4))) || (mcol && ((pj < 4) != (qj < 4)));
    relt[u] = mk ? -1e30f : relp[h * 225 + (pi - qi + 7) * 15 + (pj - qj + 7)];
  }
}

// One block per (batch, window). 512 threads = 8 waves.
__global__ __launch_bounds__(512, 2) void swin_mfma(
    const float* __restrict__ x, const float* __restrict__ bqkv,
    const float* __restrict__ bout,
    const short* __restrict__ wqkvT, const short* __restrict__ wH,
    const float* __restrict__ relt, float* __restrict__ out)
{
  __shared__ __align__(16) char lds[LDS_TOT];

  const int tx = threadIdx.x;
  const int w  = tx >> 6;         // wave 0..7
  const int l  = tx & 63;         // lane
  const int g  = l >> 4;          // k-group 0..3
  const int li = l & 15;          // row/col within fragment

  const int b   = blockIdx.x >> 10;
  const int wdw = blockIdx.x & 1023;
  const int wh  = wdw >> 5, wwi = wdw & 31;

  // ---- Phase 0: stage x window (rolled -4) as bf16 into LDS ----
  for (int i = 0; i < 8; ++i) {
    int idx = tx + i * 512;       // 0..4095
    int p = idx >> 6, c4 = idx & 63;
    int pi = p >> 3, pj = p & 7;
    int sr = (wh * 8 + pi + 4) & 255;
    int sc = (wwi * 8 + pj + 4) & 255;
    f32x4 v = *(const f32x4*)(x + ((((size_t)b * 256 + sr) * 256 + sc) * 256 + c4 * 4));
    u32x2 uu;
    uu.x = cvt2(v[0], v[1]);
    uu.y = cvt2(v[2], v[3]);
    *(u32x2*)(lds + LDS_XS + swz512(p, c4 * 8)) = uu;
  }
  __syncthreads();

  // ---- Phase 1: QKV GEMM. Wave w: Q/K col-blocks w*4..w*4+3 (swapped operands,
  //      C = [outcol][token]); V col-blocks w*2, w*2+1 (normal, C = [token][vcol]). ----
  {
    f32x4 acc[6][4];
    #pragma unroll
    for (int j = 0; j < 6; ++j)
      #pragma unroll
      for (int rb = 0; rb < 4; ++rb)
        acc[j][rb] = (f32x4){0.f, 0.f, 0.f, 0.f};

    int ocol[6];
    #pragma unroll
    for (int j = 0; j < 4; ++j) ocol[j] = (w * 4 + j) * 16 + li;
    #pragma unroll
    for (int j = 4; j < 6; ++j) ocol[j] = 512 + (w * 2 + (j - 4)) * 16 + li;

    s16x8 bcur[6], bnext[6];
    #pragma unroll
    for (int j = 0; j < 6; ++j)
      bcur[j] = *(const s16x8*)(wqkvT + (size_t)ocol[j] * 256 + g * 8);

    #pragma unroll
    for (int kk = 0; kk < 8; ++kk) {
      s16x8 a[4];
      #pragma unroll
      for (int rb = 0; rb < 4; ++rb)
        a[rb] = *(const s16x8*)(lds + LDS_XS + swz512(rb * 16 + li, kk * 64 + g * 16));
      if (kk < 7) {
        #pragma unroll
        for (int j = 0; j < 6; ++j)
          bnext[j] = *(const s16x8*)(wqkvT + (size_t)ocol[j] * 256 + (kk + 1) * 32 + g * 8);
      }
      #pragma unroll
      for (int j = 0; j < 4; ++j)          // Q,K: swapped -> C[outcol][token]
        #pragma unroll
        for (int rb = 0; rb < 4; ++rb)
          acc[j][rb] = mfma16(bcur[j], a[rb], acc[j][rb]);
      #pragma unroll
      for (int j = 4; j < 6; ++j)          // V: normal -> C[token][vcol]
        #pragma unroll
        for (int rb = 0; rb < 4; ++rb)
          acc[j][rb] = mfma16(a[rb], bcur[j], acc[j][rb]);
      if (kk < 7) {
        #pragma unroll
        for (int j = 0; j < 6; ++j) bcur[j] = bnext[j];
      }
    }

    // Packed b64 stores.
    #pragma unroll
    for (int j = 0; j < 4; ++j) {          // Q or K: row=token(rb*16+li), 4 consec cols
      const int cb = w * 4 + j;
      if (cb < 16) {                       // Q (pre-scaled)
        f32x4 bq = *(const f32x4*)(bqkv + cb * 16 + g * 4);
        #pragma unroll
        for (int rb = 0; rb < 4; ++rb) {
          const float SC = 0.17677669529663687f;
          u32x2 uu;
          uu.x = cvt2((acc[j][rb][0] + bq[0]) * SC, (acc[j][rb][1] + bq[1]) * SC);
          uu.y = cvt2((acc[j][rb][2] + bq[2]) * SC, (acc[j][rb][3] + bq[3]) * SC);
          *(u32x2*)(lds + LDS_QS + swz512(rb * 16 + li, cb * 32 + g * 8)) = uu;
        }
      } else {                             // K
        f32x4 bk = *(const f32x4*)(bqkv + 256 + (cb - 16) * 16 + g * 4);
        #pragma unroll
        for (int rb = 0; rb < 4; ++rb) {
          u32x2 uu;
          uu.x = cvt2(acc[j][rb][0] + bk[0], acc[j][rb][1] + bk[1]);
          uu.y = cvt2(acc[j][rb][2] + bk[2], acc[j][rb][3] + bk[3]);
          *(u32x2*)(lds + LDS_KS + swz512(rb * 16 + li, (cb - 16) * 32 + g * 8)) = uu;
        }
      }
    }
    #pragma unroll
    for (int j = 4; j < 6; ++j) {          // V -> VT[d][token]
      const int d = (w * 2 + (j - 4)) * 16 + li;
      const float bv = bqkv[512 + d];
      #pragma unroll
      for (int rb = 0; rb < 4; ++rb) {
        u32x2 uu;
        uu.x = cvt2(acc[j][rb][0] + bv, acc[j][rb][1] + bv);
        uu.y = cvt2(acc[j][rb][2] + bv, acc[j][rb][3] + bv);
        *(u32x2*)(lds + LDS_VT + swz128(d, rb * 32 + g * 8)) = uu;
      }
    }
  }
  __syncthreads();

  // ---- Phase 2: attention. Wave w: heads hp*2+(w>>2), rows (w&3)*16..+15. No barriers. ----
  {
    const int rvar = ((wh == 31) ? 2 : 0) | ((wwi == 31) ? 1 : 0);
    const int hsel = w >> 2, strip = w & 3, p0 = strip * 16;
    const short ONE = (short)0x3F80;
    const s16x8 ones = {ONE, ONE, ONE, ONE, ONE, ONE, ONE, ONE};
    char* prbase = lds + LDS_PR + hsel * 8192;

    #pragma unroll
    for (int hp = 0; hp < 4; ++hp) {
      const int h = hp * 2 + hsel;

      // masked rel_pos C-init (coalesced f32x4 from L2 table)
      f32x4 rc[4];
      #pragma unroll
      for (int qt = 0; qt < 4; ++qt)
        rc[qt] = *(const f32x4*)(relt + ((((rvar * 8 + h) * 4 + qt) * 4 + strip) * 64 + l) * 4);

      // simT[qt] (m=q, n=p)
      s16x8 qf = *(const s16x8*)(lds + LDS_QS + swz512(p0 + li, h * 64 + g * 16));
      f32x4 simT[4];
      #pragma unroll
      for (int qt = 0; qt < 4; ++qt) {
        s16x8 kf = *(const s16x8*)(lds + LDS_KS + swz512(qt * 16 + li, h * 64 + g * 16));
        simT[qt] = mfma16(kf, qf, rc[qt]);
      }

      // P' = exp(simT) (no-max softmax; masked = exp(-1e30) = 0), packed b64 store
      #pragma unroll
      for (int qt = 0; qt < 4; ++qt) {
        u32x2 uu;
        uu.x = cvt2(__expf(simT[qt][0]), __expf(simT[qt][1]));
        uu.y = cvt2(__expf(simT[qt][2]), __expf(simT[qt][3]));
        *(u32x2*)(prbase + swz128(p0 + li, qt * 32 + g * 8)) = uu;
      }

      // P' fragments (B operand for both sums and attnT)
      s16x8 pf[2];
      #pragma unroll
      for (int ks = 0; ks < 2; ++ks)
        pf[ks] = *(const s16x8*)(prbase + swz128(p0 + li, ks * 64 + g * 16));

      f32x4 s = (f32x4){0.f, 0.f, 0.f, 0.f};
      f32x4 at0 = (f32x4){0.f, 0.f, 0.f, 0.f};
      f32x4 at1 = (f32x4){0.f, 0.f, 0.f, 0.f};
      #pragma unroll
      for (int ks = 0; ks < 2; ++ks) {
        s = mfma16(ones, pf[ks], s);
        s16x8 vf0 = *(const s16x8*)(lds + LDS_VT + swz128(h * 32 + li, ks * 64 + g * 16));
        s16x8 vf1 = *(const s16x8*)(lds + LDS_VT + swz128(h * 32 + 16 + li, ks * 64 + g * 16));
        at0 = mfma16(vf0, pf[ks], at0);
        at1 = mfma16(vf1, pf[ks], at1);
      }
      const float rinv = 1.0f / s[0];

      // attn fp16 packed store (single buffer, XS region)
      #pragma unroll
      for (int dt = 0; dt < 2; ++dt) {
        const f32x4 at = dt ? at1 : at0;
        u32x2 hh;
        hh.x = cvt2h(at[0] * rinv, at[1] * rinv);
        hh.y = cvt2h(at[2] * rinv, at[3] * rinv);
        *(u32x2*)(lds + LDS_XS + swz512(p0 + li, h * 64 + dt * 32 + g * 8)) = hh;
      }
    }
  }
  __syncthreads();

  // ---- Phase 3: out-proj, single-term fp16. Wave w owns 2 col-blocks. ----
  {
    f32x4 acc2[2][4];
    #pragma unroll
    for (int c = 0; c < 2; ++c)
      #pragma unroll
      for (int rb = 0; rb < 4; ++rb)
        acc2[c][rb] = (f32x4){0.f, 0.f, 0.f, 0.f};

    s16x8 bc[2], bn[2];
    #pragma unroll
    for (int c = 0; c < 2; ++c)
      bc[c] = *(const s16x8*)(wH + (size_t)((w * 2 + c) * 16 + li) * 256 + g * 8);

    #pragma unroll
    for (int kk = 0; kk < 8; ++kk) {
      s16x8 a[4];
      #pragma unroll
      for (int rb = 0; rb < 4; ++rb)
        a[rb] = *(const s16x8*)(lds + LDS_XS + swz512(rb * 16 + li, kk * 64 + g * 16));
      if (kk < 7) {
        #pragma unroll
        for (int c = 0; c < 2; ++c)
          bn[c] = *(const s16x8*)(wH + (size_t)((w * 2 + c) * 16 + li) * 256
                                  + (kk + 1) * 32 + g * 8);
      }
      #pragma unroll
      for (int c = 0; c < 2; ++c)
        #pragma unroll
        for (int rb = 0; rb < 4; ++rb)
          acc2[c][rb] = mfma16h(a[rb], bc[c], acc2[c][rb]);
      if (kk < 7) {
        #pragma unroll
        for (int c = 0; c < 2; ++c) bc[c] = bn[c];
      }
    }

    #pragma unroll
    for (int c = 0; c < 2; ++c) {
      const int n = (w * 2 + c) * 16 + li;
      const float bo = bout[n];
      #pragma unroll
      for (int rb = 0; rb < 4; ++rb)
        #pragma unroll
        for (int r = 0; r < 4; ++r) {
          int m = rb * 16 + g * 4 + r;
          int pi = m >> 3, pj = m & 7;
          int dr = (wh * 8 + pi + 4) & 255;
          int dc = (wwi * 8 + pj + 4) & 255;
          out[(((size_t)b * 256 + dr) * 256 + dc) * 256 + n] = acc2[c][rb][r] + bo;
        }
    }
  }
}

extern "C" void kernel_launch(void* const* d_in, const int* in_sizes, int n_in,
                              void* d_out, int out_size, void* d_ws, size_t ws_size,
                              hipStream_t stream) {
  (void)in_sizes; (void)n_in; (void)out_size; (void)ws_size;
  const float* x    = (const float*)d_in[0];
  const float* Wqkv = (const float*)d_in[1];
  const float* bqkv = (const float*)d_in[2];
  const float* relp = (const float*)d_in[3];
  const float* Wout = (const float*)d_in[4];
  const float* bout = (const float*)d_in[5];
  float* out = (float*)d_out;

  short* wqkvT = (short*)d_ws;                  // 768*256 bf16
  short* wH    = wqkvT + 768 * 256;             // 256*256 fp16
  float* relt  = (float*)(wH + 256 * 256);      // 4*8*4*4*256 f32 = 512KB

  hipLaunchKernelGGL(prep_w, dim3(1536), dim3(256), 0, stream,
                     Wqkv, Wout, relp, wqkvT, wH, relt);
  hipLaunchKernelGGL(swin_mfma, dim3(4096), dim3(512), 0, stream,
                     x, bqkv, bout, wqkvT, wH, relt, out);
}